// Round 5
// baseline (133.599 us; speedup 1.0000x reference)
//
#include <hip/hip_runtime.h>

typedef float v2f __attribute__((ext_vector_type(2)));

// ---- problem ----
// x:[4,16,8,64,64] f32, w_q/w_k/w_v:[64,8] f32, w_p:[2] f32
// out:[4,16,64,64,64] f32
// Attention batch B = bb*64 + o (raw-reinterpret trick):
//   q-side: channel i (all 16), conv row o
//   k/v-side: channel o>>2 (fixed), conv rows (o&3)*16 + j
//   uk gets +2*pe; scaling 0.125; residual = mean over m of x[bb, i].
// R4: software-pipelined i-loop (ping-pong q prefetch) to hide L2 latency.

__global__ __launch_bounds__(256, 1) void adapt_attn(
    const float* __restrict__ x,  const float* __restrict__ wq,
    const float* __restrict__ wk, const float* __restrict__ wv,
    const float* __restrict__ wp, float* __restrict__ out)
{
    __shared__ __align__(16) float s_wk[128];   // w_k rows (o&3)*16..+16, [16][8]
    __shared__ __align__(16) float s_wv[128];
    __shared__ float s_wq[8];                   // w_q row o, pre-scaled by 0.125

    const int tid = threadIdx.x;
    const int bid = blockIdx.x;           // 1024 blocks = 4 bb * 64 o * 4 chunks
    const int bb    = bid >> 8;
    const int o     = (bid >> 2) & 63;    // block-uniform
    const int patch = ((bid & 3) << 8) + tid;   // 0..1023
    const int r   = o & 3;
    const int qch = o >> 2;

    if (tid < 128) {
        s_wk[tid] = wk[(r << 7) + tid];   // tid = j*8+m
        s_wv[tid] = wv[(r << 7) + tid];
    } else if (tid < 136) {
        s_wq[tid - 128] = 0.125f * wq[(o << 3) + (tid - 128)];
    }
    __syncthreads();

    const int hh = patch >> 5, ww = patch & 31;
    const int y0 = hh << 1;

    // pe(y,x) = wp0*locx + wp1*locy, loc(t) = -1 + 2t/63 ; uk += 2*pe
    const float wp0 = wp[0];
    const float wp1 = wp[1];
    const float step = 2.0f / 63.0f;
    const float lx0 = -1.0f + step * (float)(ww << 1);
    const float lx1 = lx0 + step;
    const float ly0 = -1.0f + step * (float)y0;
    const float ly1 = ly0 + step;
    v2f pea = { 2.0f * (wp0 * lx0 + wp1 * ly0), 2.0f * (wp0 * lx1 + wp1 * ly0) };
    v2f peb = { 2.0f * (wp0 * lx0 + wp1 * ly1), 2.0f * (wp0 * lx1 + wp1 * ly1) };

    const v2f* __restrict__ x2 = (const v2f*)x;
    // v2f strides: channel=16384, m=2048, row=32
    const int sp_off = y0 * 32 + ww;

    // ---- k/v channel pixels ----
    v2f xa[8], xb[8];
    {
        const int basek = ((bb << 4) + qch) * 16384 + sp_off;
        #pragma unroll
        for (int m = 0; m < 8; m++) {
            xa[m] = x2[basek + m * 2048];
            xb[m] = x2[basek + m * 2048 + 32];
        }
    }

    // ---- uk/uv[j] as pixel-pair vectors ----
    v2f uka[16], ukb[16], uva[16], uvb[16];
    const float4* wk4 = (const float4*)s_wk;
    const float4* wv4 = (const float4*)s_wv;
    #pragma unroll
    for (int j = 0; j < 16; j++) {
        const float4 w0 = wk4[j * 2], w1 = wk4[j * 2 + 1];
        const float4 c0 = wv4[j * 2], c1 = wv4[j * 2 + 1];
        v2f ka = pea, kb = peb;
        v2f va = {0.f, 0.f}, vb = {0.f, 0.f};
        ka += xa[0] * w0.x; kb += xb[0] * w0.x; va += xa[0] * c0.x; vb += xb[0] * c0.x;
        ka += xa[1] * w0.y; kb += xb[1] * w0.y; va += xa[1] * c0.y; vb += xb[1] * c0.y;
        ka += xa[2] * w0.z; kb += xb[2] * w0.z; va += xa[2] * c0.z; vb += xb[2] * c0.z;
        ka += xa[3] * w0.w; kb += xb[3] * w0.w; va += xa[3] * c0.w; vb += xb[3] * c0.w;
        ka += xa[4] * w1.x; kb += xb[4] * w1.x; va += xa[4] * c1.x; vb += xb[4] * c1.x;
        ka += xa[5] * w1.y; kb += xb[5] * w1.y; va += xa[5] * c1.y; vb += xb[5] * c1.y;
        ka += xa[6] * w1.z; kb += xb[6] * w1.z; va += xa[6] * c1.z; vb += xb[6] * c1.z;
        ka += xa[7] * w1.w; kb += xb[7] * w1.w; va += xa[7] * c1.w; vb += xb[7] * c1.w;
        uka[j] = ka; ukb[j] = kb; uva[j] = va; uvb[j] = vb;
    }

    // w_q row in registers
    float wqr[8];
    #pragma unroll
    for (int m = 0; m < 8; m++) wqr[m] = s_wq[m];

    v2f* __restrict__ out2 = (v2f*)out;
    const int baseq0 = (bb << 4) * 16384 + sp_off;            // v2f units
    const int obase0 = ((bb << 4) * 64 + o) * 2048 + sp_off;  // v2f units

    // ---- software-pipelined loop over 16 q channels ----
    v2f qA[8], qB[8];    // buffer 0: rows y0 / y0+1
    v2f pA[8], pB[8];    // buffer 1 (prefetch)

    auto loadq = [&](v2f* ra, v2f* rb, int i) {
        const int bq = baseq0 + i * 16384;
        #pragma unroll
        for (int m = 0; m < 8; m++) {
            ra[m] = x2[bq + m * 2048];
            rb[m] = x2[bq + m * 2048 + 32];
        }
    };

    auto compute = [&](const v2f* ra, const v2f* rb, int i) {
        v2f uqa = {0.f, 0.f}, uqb = {0.f, 0.f};
        v2f rsa = {0.f, 0.f}, rsb = {0.f, 0.f};
        #pragma unroll
        for (int m = 0; m < 8; m++) {
            uqa += ra[m] * wqr[m];   // wqr pre-scaled by 0.125
            uqb += rb[m] * wqr[m];
            rsa += ra[m];
            rsb += rb[m];
        }
        // att + softmax (no max-subtract: |att| << 1, overflow impossible)
        float att[16];
        float sum = 0.f;
        #pragma unroll
        for (int j = 0; j < 16; j++) {
            v2f t = uqa * uka[j];
            t += uqb * ukb[j];
            const float e = __expf(t.x + t.y);
            att[j] = e;
            sum += e;
        }
        const float rcp = 1.0f / sum;
        v2f oa = {0.f, 0.f}, ob = {0.f, 0.f};
        #pragma unroll
        for (int j = 0; j < 16; j++) {
            oa += uva[j] * att[j];
            ob += uvb[j] * att[j];
        }
        oa = oa * rcp + rsa * 0.125f;
        ob = ob * rcp + rsb * 0.125f;
        const int obi = obase0 + i * 131072;
        out2[obi]      = oa;
        out2[obi + 32] = ob;
    };

    loadq(qA, qB, 0);
    #pragma unroll 1
    for (int ii = 0; ii < 16; ii += 2) {
        loadq(pA, pB, ii + 1);          // prefetch odd
        compute(qA, qB, ii);            // compute even (hides odd's latency)
        const int nxt = (ii + 2 < 16) ? ii + 2 : 0;   // benign wrap on last
        loadq(qA, qB, nxt);             // prefetch next even
        compute(pA, pB, ii + 1);        // compute odd (hides even's latency)
    }
}

extern "C" void kernel_launch(void* const* d_in, const int* in_sizes, int n_in,
                              void* d_out, int out_size, void* d_ws, size_t ws_size,
                              hipStream_t stream) {
    const float* x  = (const float*)d_in[0];
    const float* wq = (const float*)d_in[1];
    const float* wk = (const float*)d_in[2];
    const float* wv = (const float*)d_in[3];
    const float* wp = (const float*)d_in[4];
    float* out = (float*)d_out;
    adapt_attn<<<dim3(1024), dim3(256), 0, stream>>>(x, wq, wk, wv, wp, out);
}

// Round 6
// 125.025 us; speedup vs baseline: 1.0686x; 1.0686x over previous
//
#include <hip/hip_runtime.h>

typedef float v2f __attribute__((ext_vector_type(2)));

// ---- problem ----
// x:[4,16,8,64,64] f32, w_q/w_k/w_v:[64,8] f32, w_p:[2] f32
// out:[4,16,64,64,64] f32
// Attention batch B = bb*64 + o (raw-reinterpret trick):
//   q-side: channel i (all 16), conv row o
//   k/v-side: channel o>>2 (fixed), conv rows (o&3)*16 + j
//   uk gets +2*pe; scaling 0.125 folded into w_q; residual = mean over m.
// R5 restructure: block = (bb, o, 16-patch tile); 3 LDS stages;
// thread = (patch,(row,m)) -> (patch,j) -> (patch,i). 16x more blocks,
// ~10x smaller threads => TLP instead of per-thread ILP.

__global__ __launch_bounds__(256, 6) void adapt_attn(
    const float* __restrict__ x,  const float* __restrict__ wq,
    const float* __restrict__ wk, const float* __restrict__ wv,
    const float* __restrict__ wp, float* __restrict__ out)
{
    __shared__ __align__(16) float s_wk[128];   // w_k rows r*16..r*16+15, [16][8]
    __shared__ __align__(16) float s_wv[128];
    __shared__ float  s_wq[8];                  // w_q row o, pre-scaled by 0.125
    __shared__ v2f    s_xk[8][2][16];           // [m][row][p] k/v-channel pixel pairs
    __shared__ float4 s_uk[16][16];             // [j][p] : (y0x0,y0x1,y1x0,y1x1)
    __shared__ float4 s_uv[16][16];

    const int tid = threadIdx.x;
    const int bid = blockIdx.x;            // ((bb*64 + o)*64) + tile
    const int tile = bid & 63;
    const int o    = (bid >> 6) & 63;
    const int bb   = bid >> 12;
    const int r = o & 3, qch = o >> 2;
    const int y0  = (tile >> 1) << 1;      // patch row * 2
    const int ww0 = (tile & 1) << 4;       // first patch col (v2f units)

    // stage 0: weights -> LDS
    if (tid < 128) {
        s_wk[tid] = wk[(r << 7) + tid];    // tid = j*8+m
        s_wv[tid] = wv[(r << 7) + tid];
    } else if (tid < 136) {
        s_wq[tid - 128] = 0.125f * wq[(o << 3) + (tid - 128)];
    }

    const v2f* __restrict__ x2 = (const v2f*)x;
    // v2f strides: channel = 16384, m = 2048, row = 32

    // stage 1: k/v channel pixels -> LDS (coalesced: lanes 0-15 consecutive)
    {
        const int p = tid & 15, row = (tid >> 4) & 1, m = tid >> 5;
        const int g = ((bb << 4) + qch) * 16384 + m * 2048 + (y0 + row) * 32 + ww0 + p;
        s_xk[m][row][p] = x2[g];
    }
    __syncthreads();

    // stage 2: thread (p, j) builds uk/uv[j][p]
    {
        const int p = tid & 15, j = tid >> 4;
        const float wp0 = wp[0], wp1 = wp[1];
        const float step = 2.0f / 63.0f;
        const int wwp = ww0 + p;
        const float lx0 = -1.0f + step * (float)(wwp << 1);
        const float lx1 = lx0 + step;
        const float ly0 = -1.0f + step * (float)y0;
        const float ly1 = ly0 + step;
        v2f ka = { 2.0f * (wp0 * lx0 + wp1 * ly0), 2.0f * (wp0 * lx1 + wp1 * ly0) };
        v2f kb = { 2.0f * (wp0 * lx0 + wp1 * ly1), 2.0f * (wp0 * lx1 + wp1 * ly1) };
        v2f va = {0.f, 0.f}, vb = {0.f, 0.f};

        float wkj[8], wvj[8];
        *(float4*)&wkj[0] = ((const float4*)s_wk)[j * 2];
        *(float4*)&wkj[4] = ((const float4*)s_wk)[j * 2 + 1];
        *(float4*)&wvj[0] = ((const float4*)s_wv)[j * 2];
        *(float4*)&wvj[4] = ((const float4*)s_wv)[j * 2 + 1];

        #pragma unroll
        for (int m = 0; m < 8; m++) {
            const v2f xa = s_xk[m][0][p];
            const v2f xb = s_xk[m][1][p];
            ka += xa * wkj[m]; kb += xb * wkj[m];
            va += xa * wvj[m]; vb += xb * wvj[m];
        }
        s_uk[j][p] = make_float4(ka.x, ka.y, kb.x, kb.y);
        s_uv[j][p] = make_float4(va.x, va.y, vb.x, vb.y);
    }
    __syncthreads();

    // stage 3: thread (p, i) -> q-conv, softmax over j, AV, store
    {
        const int p = tid & 15, i = tid >> 4;
        float wqr[8];
        #pragma unroll
        for (int m = 0; m < 8; m++) wqr[m] = s_wq[m];

        const int bq = ((bb << 4) + i) * 16384 + y0 * 32 + ww0 + p;
        v2f qa[8], qb[8];
        #pragma unroll
        for (int m = 0; m < 8; m++) {       // lanes 0-15: i uniform, p 0..15 -> coalesced
            qa[m] = x2[bq + m * 2048];
            qb[m] = x2[bq + m * 2048 + 32];
        }
        v2f uqa = {0.f,0.f}, uqb = {0.f,0.f}, rsa = {0.f,0.f}, rsb = {0.f,0.f};
        #pragma unroll
        for (int m = 0; m < 8; m++) {
            uqa += qa[m] * wqr[m];          // wqr pre-scaled by 0.125
            uqb += qb[m] * wqr[m];
            rsa += qa[m];
            rsb += qb[m];
        }

        // att + softmax (no max-subtract: |att| << 1, overflow impossible)
        float att[16];
        float sum = 0.f;
        #pragma unroll
        for (int j = 0; j < 16; j++) {
            const float4 k4 = s_uk[j][p];   // 16 unique addrs, 2-way banks: free
            v2f t = uqa * (v2f){k4.x, k4.y};
            t += uqb * (v2f){k4.z, k4.w};
            const float e = __expf(t.x + t.y);
            att[j] = e;
            sum += e;
        }
        const float rcp = 1.0f / sum;

        v2f oa = {0.f,0.f}, ob = {0.f,0.f};
        #pragma unroll
        for (int j = 0; j < 16; j++) {
            const float4 v4 = s_uv[j][p];
            oa += (v2f){v4.x, v4.y} * att[j];
            ob += (v2f){v4.z, v4.w} * att[j];
        }
        oa = oa * rcp + rsa * 0.125f;       // residual = mean over m
        ob = ob * rcp + rsb * 0.125f;

        v2f* __restrict__ out2 = (v2f*)out;
        const int obi = (((bb << 4) + i) * 64 + o) * 2048 + y0 * 32 + ww0 + p;
        out2[obi]      = oa;    // row y0   (lanes 0-15 consecutive)
        out2[obi + 32] = ob;    // row y0+1
    }
}

extern "C" void kernel_launch(void* const* d_in, const int* in_sizes, int n_in,
                              void* d_out, int out_size, void* d_ws, size_t ws_size,
                              hipStream_t stream) {
    const float* x  = (const float*)d_in[0];
    const float* wq = (const float*)d_in[1];
    const float* wk = (const float*)d_in[2];
    const float* wv = (const float*)d_in[3];
    const float* wp = (const float*)d_in[4];
    float* out = (float*)d_out;
    // 4 bb * 64 o * 64 tiles = 16384 blocks of 256 threads
    adapt_attn<<<dim3(16384), dim3(256), 0, stream>>>(x, wq, wk, wv, wp, out);
}

// Round 9
// 120.961 us; speedup vs baseline: 1.1045x; 1.0336x over previous
//
#include <hip/hip_runtime.h>

typedef float v2f __attribute__((ext_vector_type(2)));

// ---- problem ----
// x:[4,16,8,64,64] f32, w_q/w_k/w_v:[64,8] f32, w_p:[2] f32
// out:[4,16,64,64,64] f32
// Attention batch B = bb*64 + o: q-side channel i (all 16) row o;
// k/v-side channel o>>2, rows (o&3)*16+j; uk += 2*pe; scale 0.125 folded
// into w_q; residual = mean over m; single-pass softmax (no max-subtract:
// |logit| << 88): out = (sum_j e_j*uv_j)/(sum_j e_j).
// R9 = R6 skeleton (256-thr blocks, proven style) + ONE delta:
// 2 tiles/block, stage-3 F=2 i-blocking (thread = (p, 2-i-group, tile)).
// launch_bounds (256,4): 4 blocks/CU x 21.5KB = 86KB < 160KB LDS (feasible;
// R7/R8's (128,4) implied 8 blocks x 21.5KB = 172KB > 160KB -> dead launch).

__global__ __launch_bounds__(256, 4) void adapt_attn(
    const float* __restrict__ x,  const float* __restrict__ wq,
    const float* __restrict__ wk, const float* __restrict__ wv,
    const float* __restrict__ wp, float* __restrict__ out)
{
    __shared__ __align__(16) float s_wk[128];   // w_k rows r*16..+15, [16][8]
    __shared__ __align__(16) float s_wv[128];
    __shared__ float  s_wq[8];                  // w_q row o, pre-scaled 0.125
    __shared__ v2f    s_xk[2][8][2][16];        // [t][m][row][p]
    __shared__ float4 s_uk[2][16][16];          // [t][j][p]: (y0x0,y0x1,y1x0,y1x1)
    __shared__ float4 s_uv[2][16][16];

    const int tid = threadIdx.x;          // 0..255
    const int bid = blockIdx.x;           // ((bb*64+o)*32)+tg ; 8192 blocks
    const int tg = bid & 31;
    const int o  = (bid >> 5) & 63;
    const int bb = bid >> 11;
    const int r = o & 3, qch = o >> 2;

    // stage 0: weights (R6-identical)
    if (tid < 128) {
        s_wk[tid] = wk[(r << 7) + tid];   // tid = j*8+m
        s_wv[tid] = wv[(r << 7) + tid];
    } else if (tid < 136) {
        s_wq[tid - 128] = 0.125f * wq[(o << 3) + (tid - 128)];
    }

    const v2f* __restrict__ x2 = (const v2f*)x;
    // v2f strides: channel 16384, m 2048, row 32

    // stage 1: k/v-channel pixels for both tiles -> LDS (coalesced)
    #pragma unroll
    for (int it = 0; it < 2; it++) {
        const int idx = it * 256 + tid;           // 512 = 2t * 8m * 2row * 16p
        const int p = idx & 15, row = (idx >> 4) & 1, m = (idx >> 5) & 7, t = idx >> 8;
        const int tile = tg * 2 + t;
        const int y0 = (tile >> 1) << 1, ww0 = (tile & 1) << 4;
        s_xk[t][m][row][p] =
            x2[((bb * 16 + qch) * 8 + m) * 2048 + (y0 + row) * 32 + ww0 + p];
    }
    __syncthreads();

    // stage 2: build uk/uv[t][j][p]
    const float wp0 = wp[0], wp1 = wp[1];
    const float step = 2.0f / 63.0f;
    #pragma unroll
    for (int it = 0; it < 2; it++) {
        const int idx = it * 256 + tid;           // 512 = 2t * 16j * 16p
        const int p = idx & 15, j = (idx >> 4) & 15, t = idx >> 8;
        const int tile = tg * 2 + t;
        const int y0 = (tile >> 1) << 1, ww0 = (tile & 1) << 4;
        const int wwp = ww0 + p;
        const float lx0 = -1.0f + step * (float)(wwp << 1);
        const float lx1 = lx0 + step;
        const float ly0 = -1.0f + step * (float)y0;
        const float ly1 = ly0 + step;
        v2f ka = { 2.0f * (wp0 * lx0 + wp1 * ly0), 2.0f * (wp0 * lx1 + wp1 * ly0) };
        v2f kb = { 2.0f * (wp0 * lx0 + wp1 * ly1), 2.0f * (wp0 * lx1 + wp1 * ly1) };
        v2f va = {0.f, 0.f}, vb = {0.f, 0.f};

        float wkj[8], wvj[8];
        *(float4*)&wkj[0] = ((const float4*)s_wk)[j * 2];
        *(float4*)&wkj[4] = ((const float4*)s_wk)[j * 2 + 1];
        *(float4*)&wvj[0] = ((const float4*)s_wv)[j * 2];
        *(float4*)&wvj[4] = ((const float4*)s_wv)[j * 2 + 1];

        #pragma unroll
        for (int m = 0; m < 8; m++) {
            const v2f xa = s_xk[t][m][0][p];
            const v2f xb = s_xk[t][m][1][p];
            ka += xa * wkj[m]; kb += xb * wkj[m];
            va += xa * wvj[m]; vb += xb * wvj[m];
        }
        s_uk[t][j][p] = make_float4(ka.x, ka.y, kb.x, kb.y);
        s_uv[t][j][p] = make_float4(va.x, va.y, vb.x, vb.y);
    }
    __syncthreads();

    // stage 3: thread (p, ig, t) handles i = ig*2, ig*2+1  (F=2)
    {
        const int p = tid & 15, ig = (tid >> 4) & 7, t = tid >> 7;
        const int tile = tg * 2 + t;
        const int y0 = (tile >> 1) << 1, ww0 = (tile & 1) << 4;
        const int sp = y0 * 32 + ww0 + p;

        float wqr[8];
        #pragma unroll
        for (int m = 0; m < 8; m++) wqr[m] = s_wq[m];

        v2f uqa[2], uqb[2], rsa[2], rsb[2];
        #pragma unroll
        for (int n = 0; n < 2; n++) {
            const int i = ig * 2 + n;
            const int bq = (bb * 16 + i) * 16384 + sp;
            v2f qa[8], qb[8];
            #pragma unroll
            for (int m = 0; m < 8; m++) {         // lanes 0-15 coalesced 128B
                qa[m] = x2[bq + m * 2048];
                qb[m] = x2[bq + m * 2048 + 32];
            }
            v2f ua = {0.f, 0.f}, ub = {0.f, 0.f}, ra = {0.f, 0.f}, rb = {0.f, 0.f};
            #pragma unroll
            for (int m = 0; m < 8; m++) {
                ua += qa[m] * wqr[m];             // wq pre-scaled by 0.125
                ub += qb[m] * wqr[m];
                ra += qa[m];
                rb += qb[m];
            }
            uqa[n] = ua; uqb[n] = ub; rsa[n] = ra; rsb[n] = rb;
        }

        // fused att + softmax + AV, one pass over j, both i's per uk/uv read
        v2f oa0 = {0.f, 0.f}, ob0 = {0.f, 0.f};
        v2f oa1 = {0.f, 0.f}, ob1 = {0.f, 0.f};
        float sum0 = 0.f, sum1 = 0.f;

        #pragma unroll
        for (int j = 0; j < 16; j++) {
            const float4 k4 = s_uk[t][j][p];      // 2-way bank alias: free
            const float4 v4 = s_uv[t][j][p];
            const v2f ka = {k4.x, k4.y}, kb = {k4.z, k4.w};
            const v2f va = {v4.x, v4.y}, vb = {v4.z, v4.w};

            v2f t0 = uqa[0] * ka;
            t0 += uqb[0] * kb;
            const float e0 = __expf(t0.x + t0.y);
            sum0 += e0;
            oa0 += va * e0;
            ob0 += vb * e0;

            v2f t1 = uqa[1] * ka;
            t1 += uqb[1] * kb;
            const float e1 = __expf(t1.x + t1.y);
            sum1 += e1;
            oa1 += va * e1;
            ob1 += vb * e1;
        }

        v2f* __restrict__ out2 = (v2f*)out;
        {
            const int i = ig * 2;
            const float rcp = 1.0f / sum0;
            const v2f outa = oa0 * rcp + rsa[0] * 0.125f;   // residual = mean/m
            const v2f outb = ob0 * rcp + rsb[0] * 0.125f;
            const int obi = ((bb * 16 + i) * 64 + o) * 2048 + sp;
            out2[obi]      = outa;    // row y0
            out2[obi + 32] = outb;    // row y0+1
        }
        {
            const int i = ig * 2 + 1;
            const float rcp = 1.0f / sum1;
            const v2f outa = oa1 * rcp + rsa[1] * 0.125f;
            const v2f outb = ob1 * rcp + rsb[1] * 0.125f;
            const int obi = ((bb * 16 + i) * 64 + o) * 2048 + sp;
            out2[obi]      = outa;
            out2[obi + 32] = outb;
        }
    }
}

extern "C" void kernel_launch(void* const* d_in, const int* in_sizes, int n_in,
                              void* d_out, int out_size, void* d_ws, size_t ws_size,
                              hipStream_t stream) {
    const float* x  = (const float*)d_in[0];
    const float* wq = (const float*)d_in[1];
    const float* wk = (const float*)d_in[2];
    const float* wv = (const float*)d_in[3];
    const float* wp = (const float*)d_in[4];
    float* out = (float*)d_out;
    // 4 bb * 64 o * 32 tile-pairs = 8192 blocks of 256 threads
    adapt_attn<<<dim3(8192), dim3(256), 0, stream>>>(x, wq, wk, wv, wp, out);
}

// Round 10
// 120.942 us; speedup vs baseline: 1.1047x; 1.0002x over previous
//
#include <hip/hip_runtime.h>

typedef float v2f __attribute__((ext_vector_type(2)));

// ---- problem ----
// x:[4,16,8,64,64] f32, w_q/w_k/w_v:[64,8] f32, w_p:[2] f32
// out:[4,16,64,64,64] f32
// Attention batch B = bb*64 + o: q-side channel i (all 16) row o;
// k/v-side channel o>>2, rows (o&3)*16+j; uk += 2*pe; scale 0.125 folded
// into w_q; residual = mean over m; single-pass softmax (no max-subtract:
// |logit| << 88): out = (sum_j e_j*uv_j)/(sum_j e_j).
// R10 = R9 + ONE delta: stage-3 q loads + q-conv hoisted into the prologue
// (before any barrier) so L2 latency overlaps stage-1/2 work; only uq/rs
// (8 v2f) live across barriers. s_wq dropped (uniform scalar loads).

__global__ __launch_bounds__(256, 4) void adapt_attn(
    const float* __restrict__ x,  const float* __restrict__ wq,
    const float* __restrict__ wk, const float* __restrict__ wv,
    const float* __restrict__ wp, float* __restrict__ out)
{
    __shared__ __align__(16) float s_wk[128];   // w_k rows r*16..+15, [16][8]
    __shared__ __align__(16) float s_wv[128];
    __shared__ v2f    s_xk[2][8][2][16];        // [t][m][row][p]
    __shared__ float4 s_uk[2][16][16];          // [t][j][p]: (y0x0,y0x1,y1x0,y1x1)
    __shared__ float4 s_uv[2][16][16];

    const int tid = threadIdx.x;          // 0..255
    const int bid = blockIdx.x;           // ((bb*64+o)*32)+tg ; 8192 blocks
    const int tg = bid & 31;
    const int o  = (bid >> 5) & 63;
    const int bb = bid >> 11;
    const int r = o & 3, qch = o >> 2;

    const v2f* __restrict__ x2 = (const v2f*)x;
    // v2f strides: channel 16384, m 2048, row 32

    // ---- prologue A: issue stage-1 k/v staging loads ----
    v2f s1v[2];
    #pragma unroll
    for (int it = 0; it < 2; it++) {
        const int idx = it * 256 + tid;           // 512 = 2t * 8m * 2row * 16p
        const int p = idx & 15, row = (idx >> 4) & 1, m = (idx >> 5) & 7, t = idx >> 8;
        const int tile = tg * 2 + t;
        const int y0 = (tile >> 1) << 1, ww0 = (tile & 1) << 4;
        s1v[it] = x2[((bb * 16 + qch) * 8 + m) * 2048 + (y0 + row) * 32 + ww0 + p];
    }

    // ---- prologue B: issue wk/wv staging loads ----
    float wkv_k = 0.f, wkv_v = 0.f;
    if (tid < 128) {
        wkv_k = wk[(r << 7) + tid];       // tid = j*8+m
        wkv_v = wv[(r << 7) + tid];
    }

    // ---- prologue C: stage-3 mapping + issue ALL q loads ----
    const int p3 = tid & 15, ig = (tid >> 4) & 7, t3 = tid >> 7;
    const int tile3 = tg * 2 + t3;
    const int y03 = (tile3 >> 1) << 1, ww03 = (tile3 & 1) << 4;
    const int sp = y03 * 32 + ww03 + p3;

    v2f qa0[8], qb0[8], qa1[8], qb1[8];
    {
        const int bq0 = (bb * 16 + ig * 2) * 16384 + sp;
        const int bq1 = bq0 + 16384;
        #pragma unroll
        for (int m = 0; m < 8; m++) {             // lanes 0-15 coalesced 128B
            qa0[m] = x2[bq0 + m * 2048];
            qb0[m] = x2[bq0 + m * 2048 + 32];
            qa1[m] = x2[bq1 + m * 2048];
            qb1[m] = x2[bq1 + m * 2048 + 32];
        }
    }

    // ---- prologue D: LDS stores for stages 1/0 ----
    #pragma unroll
    for (int it = 0; it < 2; it++) {
        const int idx = it * 256 + tid;
        const int p = idx & 15, row = (idx >> 4) & 1, m = (idx >> 5) & 7, t = idx >> 8;
        s_xk[t][m][row][p] = s1v[it];
    }
    if (tid < 128) {
        s_wk[tid] = wkv_k;
        s_wv[tid] = wkv_v;
    }

    // ---- prologue E: q-conv + residual (hides q-load latency) ----
    float wqr[8];
    #pragma unroll
    for (int m = 0; m < 8; m++) wqr[m] = 0.125f * wq[(o << 3) + m];  // uniform

    v2f uqa0 = {0.f, 0.f}, uqb0 = {0.f, 0.f}, rsa0 = {0.f, 0.f}, rsb0 = {0.f, 0.f};
    v2f uqa1 = {0.f, 0.f}, uqb1 = {0.f, 0.f}, rsa1 = {0.f, 0.f}, rsb1 = {0.f, 0.f};
    #pragma unroll
    for (int m = 0; m < 8; m++) {
        uqa0 += qa0[m] * wqr[m];          // wq pre-scaled by 0.125
        uqb0 += qb0[m] * wqr[m];
        rsa0 += qa0[m];
        rsb0 += qb0[m];
        uqa1 += qa1[m] * wqr[m];
        uqb1 += qb1[m] * wqr[m];
        rsa1 += qa1[m];
        rsb1 += qb1[m];
    }
    __syncthreads();

    // ---- stage 2: build uk/uv[t][j][p] (R9-identical) ----
    const float wp0 = wp[0], wp1 = wp[1];
    const float step = 2.0f / 63.0f;
    #pragma unroll
    for (int it = 0; it < 2; it++) {
        const int idx = it * 256 + tid;           // 512 = 2t * 16j * 16p
        const int p = idx & 15, j = (idx >> 4) & 15, t = idx >> 8;
        const int tile = tg * 2 + t;
        const int y0 = (tile >> 1) << 1, ww0 = (tile & 1) << 4;
        const int wwp = ww0 + p;
        const float lx0 = -1.0f + step * (float)(wwp << 1);
        const float lx1 = lx0 + step;
        const float ly0 = -1.0f + step * (float)y0;
        const float ly1 = ly0 + step;
        v2f ka = { 2.0f * (wp0 * lx0 + wp1 * ly0), 2.0f * (wp0 * lx1 + wp1 * ly0) };
        v2f kb = { 2.0f * (wp0 * lx0 + wp1 * ly1), 2.0f * (wp0 * lx1 + wp1 * ly1) };
        v2f va = {0.f, 0.f}, vb = {0.f, 0.f};

        float wkj[8], wvj[8];
        *(float4*)&wkj[0] = ((const float4*)s_wk)[j * 2];
        *(float4*)&wkj[4] = ((const float4*)s_wk)[j * 2 + 1];
        *(float4*)&wvj[0] = ((const float4*)s_wv)[j * 2];
        *(float4*)&wvj[4] = ((const float4*)s_wv)[j * 2 + 1];

        #pragma unroll
        for (int m = 0; m < 8; m++) {
            const v2f xa = s_xk[t][m][0][p];
            const v2f xb = s_xk[t][m][1][p];
            ka += xa * wkj[m]; kb += xb * wkj[m];
            va += xa * wvj[m]; vb += xb * wvj[m];
        }
        s_uk[t][j][p] = make_float4(ka.x, ka.y, kb.x, kb.y);
        s_uv[t][j][p] = make_float4(va.x, va.y, vb.x, vb.y);
    }
    __syncthreads();

    // ---- stage 3: fused att + softmax + AV (R9-identical math) ----
    {
        v2f oa0 = {0.f, 0.f}, ob0 = {0.f, 0.f};
        v2f oa1 = {0.f, 0.f}, ob1 = {0.f, 0.f};
        float sum0 = 0.f, sum1 = 0.f;

        #pragma unroll
        for (int j = 0; j < 16; j++) {
            const float4 k4 = s_uk[t3][j][p3];    // 2-way bank alias: free
            const float4 v4 = s_uv[t3][j][p3];
            const v2f ka = {k4.x, k4.y}, kb = {k4.z, k4.w};
            const v2f va = {v4.x, v4.y}, vb = {v4.z, v4.w};

            v2f t0 = uqa0 * ka;
            t0 += uqb0 * kb;
            const float e0 = __expf(t0.x + t0.y);
            sum0 += e0;
            oa0 += va * e0;
            ob0 += vb * e0;

            v2f t1 = uqa1 * ka;
            t1 += uqb1 * kb;
            const float e1 = __expf(t1.x + t1.y);
            sum1 += e1;
            oa1 += va * e1;
            ob1 += vb * e1;
        }

        v2f* __restrict__ out2 = (v2f*)out;
        {
            const int i = ig * 2;
            const float rcp = 1.0f / sum0;
            const v2f outa = oa0 * rcp + rsa0 * 0.125f;   // residual = mean/m
            const v2f outb = ob0 * rcp + rsb0 * 0.125f;
            const int obi = ((bb * 16 + i) * 64 + o) * 2048 + sp;
            out2[obi]      = outa;    // row y0
            out2[obi + 32] = outb;    // row y0+1
        }
        {
            const int i = ig * 2 + 1;
            const float rcp = 1.0f / sum1;
            const v2f outa = oa1 * rcp + rsa1 * 0.125f;
            const v2f outb = ob1 * rcp + rsb1 * 0.125f;
            const int obi = ((bb * 16 + i) * 64 + o) * 2048 + sp;
            out2[obi]      = outa;
            out2[obi + 32] = outb;
        }
    }
}

extern "C" void kernel_launch(void* const* d_in, const int* in_sizes, int n_in,
                              void* d_out, int out_size, void* d_ws, size_t ws_size,
                              hipStream_t stream) {
    const float* x  = (const float*)d_in[0];
    const float* wq = (const float*)d_in[1];
    const float* wk = (const float*)d_in[2];
    const float* wv = (const float*)d_in[3];
    const float* wp = (const float*)d_in[4];
    float* out = (float*)d_out;
    // 4 bb * 64 o * 32 tile-pairs = 8192 blocks of 256 threads
    adapt_attn<<<dim3(8192), dim3(256), 0, stream>>>(x, wq, wk, wv, wp, out);
}